// Round 6
// baseline (86.708 us; speedup 1.0000x reference)
//
#include <hip/hip_runtime.h>

namespace {
constexpr int kNE = 14;
constexpr int kNC = 20;
constexpr int kCloner = 13;
constexpr int kCA = 17;   // NE + 3
constexpr int kB = 32;
constexpr int kH = 256;
constexpr int kW = 256;

constexpr int kT = 32;        // core tile
constexpr int kE = kT + 4;    // extended rows (halo 2)
constexpr int kLW = 40;       // lds row width: [w0-4, w0+36)
constexpr int kThreads = 256;
constexpr size_t kPlane = (size_t)kH * kW;
}

// pack (uint8): bits0..3 label (argmax of one-hot 0..13) | bits4..7 ca_init
// CA state (uint16): bit0 empty | bit1 active | bits4..7 fca | bits8..11 src | bit12 overwritten

// ---------------- K1: copy 19 channels + emit pack; pure streaming ----------------
__global__ __launch_bounds__(kThreads)
void k_pack_copy(const float* __restrict__ world, const float* __restrict__ info,
                 float* __restrict__ out, unsigned char* __restrict__ pack)
{
    const int g = blockIdx.x * kThreads + threadIdx.x;   // 524288 float4-groups
    const int b = g >> 14;                                // 16384 groups per plane
    const int rem = g & 16383;
    const size_t off = (size_t)rem << 2;
    const float* wb = world + (size_t)b * kNC * kPlane;
    float*       ob = out   + (size_t)b * kNC * kPlane;

    int lab[4] = {0, 0, 0, 0};
    #pragma unroll
    for (int c = 0; c < kNE; ++c) {           // one-hot channels: copy + label detect
        const float4 v = *reinterpret_cast<const float4*>(wb + (size_t)c * kPlane + off);
        if (v.x > 0.5f) lab[0] = c;           // exact one-hot: unique channel holds 1.0
        if (v.y > 0.5f) lab[1] = c;
        if (v.z > 0.5f) lab[2] = c;
        if (v.w > 0.5f) lab[3] = c;
        *reinterpret_cast<float4*>(ob + (size_t)c * kPlane + off) = v;
    }
    #pragma unroll
    for (int c = kNE; c < kNC; ++c) {         // extra channels: plain copy (skip ch17)
        if (c == kCA) continue;
        const float4 v = *reinterpret_cast<const float4*>(wb + (size_t)c * kPlane + off);
        *reinterpret_cast<float4*>(ob + (size_t)c * kPlane + off) = v;
    }
    const float4 ca4 = *reinterpret_cast<const float4*>(wb + (size_t)kCA * kPlane + off);
    uchar4 p;
    p.x = (unsigned char)(lab[0] | ((int)ca4.x << 4));
    p.y = (unsigned char)(lab[1] | ((int)ca4.y << 4));
    p.z = (unsigned char)(lab[2] | ((int)ca4.z << 4));
    p.w = (unsigned char)(lab[3] | ((int)ca4.w << 4));
    *reinterpret_cast<uchar4*>(pack + (size_t)b * kPlane + off) = p;

    if (g < kB) out[(size_t)kB * kNC * kPlane + g] = info[g];   // info passthrough
}

// one mask-evolution step: self s, neighbor ns (both CA-state words)
__device__ __forceinline__ unsigned bc_step(unsigned s, unsigned ns,
                                            const unsigned short* __restrict__ vb) {
    if ((ns & 2u) && (s & 1u)) {
        const unsigned v = (ns >> 4) & 15u;
        return (s & 0x00F0u) | vb[v] | (v << 8) | 0x1000u;
    }
    return s;
}

// ---------------- K2: CA evolution; dense ch17 write + sparse patches ----------------
__global__ __launch_bounds__(kThreads)
void k_ca(const float* __restrict__ ev, const unsigned char* __restrict__ pack,
          float* __restrict__ out)
{
    __shared__ unsigned char  sP[kE][kLW];    // packed label|ca<<4
    __shared__ unsigned short sA[kE][kLW];    // CA state after phase A
    __shared__ float sEV[kNE * kNC];
    __shared__ unsigned short sVbits[kNE];

    const int tid = threadIdx.x;
    const int b  = blockIdx.z;
    const int h0 = blockIdx.y * kT;
    const int w0 = blockIdx.x * kT;
    float* ob = out + (size_t)b * kNC * kPlane;
    const unsigned char* pb = pack + (size_t)b * kPlane;

    for (int i = tid; i < kNE * kNC; i += kThreads) sEV[i] = ev[i];
    if (tid < kNE) {
        const float e0  = ev[tid * kNC + 0];
        const float c13 = ev[tid * kNC + kCloner];
        const float c17 = ev[tid * kNC + kCA];
        unsigned short vb = 0;
        if (e0 > 0.5f) vb |= 1;                                     // empty after overwrite
        if (c13 > 0.5f && c17 != 0.0f && c17 != 13.0f) vb |= 2;     // active after overwrite
        sVbits[tid] = vb;
    }

    // pack tile+halo2 from global (uchar4; wrap keeps 4-alignment since 256%4==0)
    for (int idx = tid; idx < kE * 10; idx += kThreads) {
        const int eh = idx / 10;
        const int k  = idx - eh * 10;
        const int h = (h0 + eh - 2) & (kH - 1);
        const int w = (w0 - 4 + 4 * k) & (kW - 1);
        const uchar4 v = *reinterpret_cast<const uchar4*>(pb + (size_t)h * kW + w);
        sP[eh][4 * k + 0] = v.x;
        sP[eh][4 * k + 1] = v.y;
        sP[eh][4 * k + 2] = v.z;
        sP[eh][4 * k + 3] = v.w;
    }
    __syncthreads();

    // phase A: final CA + state init on rows 1..34, cols 3..36
    for (int idx = tid; idx < 34 * 34; idx += kThreads) {
        const int eh = idx / 34 + 1;
        const int lw = idx % 34 + 3;
        const unsigned p = sP[eh][lw];
        const unsigned lb = p & 15u;
        int fca = 0;
        if (lb == kCloner) {                 // cloner: sequentially absorb neighbor labels
            int ca = (int)(p >> 4);
            if (ca == 0 || ca == 13) ca = sP[eh + 1][lw] & 15;  // below
            if (ca == 0 || ca == 13) ca = sP[eh - 1][lw] & 15;  // above
            if (ca == 0 || ca == 13) ca = sP[eh][lw - 1] & 15;  // left
            if (ca == 0 || ca == 13) ca = sP[eh][lw + 1] & 15;  // right
            fca = ca;
        }
        unsigned short s = (unsigned short)(fca << 4);
        if (lb == 0) s |= 1;                                  // empty
        if (lb == kCloner && fca != 0 && fca != 13) s |= 2;   // active
        sA[eh][lw] = s;
    }
    __syncthreads();

    // phase B in registers: 4 direction steps over each thread's 3x6 cone (HW-verified r5)
    const int th  = tid >> 3;
    const int tw4 = (tid & 7) * 4;
    const int eh  = th + 2;          // core row in ext coords (2..33)
    const int lw0 = tw4 + 4;         // first core col (4..32)
    const size_t off4 = (size_t)(h0 + th) * kW + (w0 + tw4);

    unsigned s0[3][6];
    #pragma unroll
    for (int r = 0; r < 3; ++r)
        #pragma unroll
        for (int c = 0; c < 6; ++c)
            s0[r][c] = sA[eh - 1 + r][lw0 - 1 + c];

    unsigned s1[2][6];
    #pragma unroll
    for (int r = 0; r < 2; ++r)
        #pragma unroll
        for (int c = 0; c < 6; ++c)
            s1[r][c] = bc_step(s0[r][c], s0[r + 1][c], sVbits);   // below

    unsigned s2[6];
    #pragma unroll
    for (int c = 0; c < 6; ++c)
        s2[c] = bc_step(s1[1][c], s1[0][c], sVbits);              // above

    unsigned s3[5];
    #pragma unroll
    for (int c = 0; c < 5; ++c)
        s3[c] = bc_step(s2[c + 1], s2[c], sVbits);                // left

    unsigned s4[4];
    #pragma unroll
    for (int j = 0; j < 4; ++j)
        s4[j] = bc_step(s3[j], s3[j + 1], sVbits);                // right

    // dense ch17 write
    {
        float4 r17;
        r17.x = (s4[0] & 0x1000u) ? sEV[((s4[0] >> 8) & 15) * kNC + kCA] : (float)((s4[0] >> 4) & 15);
        r17.y = (s4[1] & 0x1000u) ? sEV[((s4[1] >> 8) & 15) * kNC + kCA] : (float)((s4[1] >> 4) & 15);
        r17.z = (s4[2] & 0x1000u) ? sEV[((s4[2] >> 8) & 15) * kNC + kCA] : (float)((s4[2] >> 4) & 15);
        r17.w = (s4[3] & 0x1000u) ? sEV[((s4[3] >> 8) & 15) * kNC + kCA] : (float)((s4[3] >> 4) & 15);
        *reinterpret_cast<float4*>(ob + (size_t)kCA * kPlane + off4) = r17;
    }

    // sparse patches: overwritten pixels get elem_vecs[src] on the other 19 channels
    #pragma unroll
    for (int j = 0; j < 4; ++j) {
        if (s4[j] & 0x1000u) {
            const float* vv = &sEV[((s4[j] >> 8) & 15) * kNC];
            float* op = ob + off4 + j;
            #pragma unroll
            for (int c = 0; c < kNC; ++c) {
                if (c == kCA) continue;
                op[(size_t)c * kPlane] = vv[c];
            }
        }
    }
}

// ---------------- Fallback (round-3 fused kernel), used only if ws too small ----------
__global__ __launch_bounds__(kThreads)
void bc_fused(const float* __restrict__ world, const float* __restrict__ ev,
              const float* __restrict__ info, float* __restrict__ out)
{
    __shared__ unsigned short sPack[kE][kLW];
    __shared__ unsigned short sA[kE][kLW];
    __shared__ unsigned short sB[kE][kLW];
    __shared__ float sEV[kNE * kNC];
    __shared__ unsigned short sVbits[kNE];

    const int tid = threadIdx.x;
    const int b  = blockIdx.z;
    const int h0 = blockIdx.y * kT;
    const int w0 = blockIdx.x * kT;
    const float* wb = world + (size_t)b * kNC * kPlane;
    float*       ob = out   + (size_t)b * kNC * kPlane;

    for (int i = tid; i < kNE * kNC; i += kThreads) sEV[i] = ev[i];
    if (tid < kNE) {
        const float e0  = ev[tid * kNC + 0];
        const float c13 = ev[tid * kNC + kCloner];
        const float c17 = ev[tid * kNC + kCA];
        unsigned short vb = 0;
        if (e0 > 0.5f) vb |= 1;
        if (c13 > 0.5f && c17 != 0.0f && c17 != 13.0f) vb |= 2;
        sVbits[tid] = vb;
    }
    for (int idx = tid; idx < kE * 10; idx += kThreads) {
        const int eh = idx / 10;
        const int k  = idx - eh * 10;
        const int h = (h0 + eh - 2) & (kH - 1);
        const int w = (w0 - 4 + 4 * k) & (kW - 1);
        const size_t off = (size_t)h * kW + w;
        int lab[4] = {0,0,0,0};
        #pragma unroll
        for (int c = 0; c < kNE; ++c) {
            const float4 v = *reinterpret_cast<const float4*>(wb + (size_t)c * kPlane + off);
            if (v.x > 0.5f) lab[0] = c;
            if (v.y > 0.5f) lab[1] = c;
            if (v.z > 0.5f) lab[2] = c;
            if (v.w > 0.5f) lab[3] = c;
        }
        const float4 ca4 = *reinterpret_cast<const float4*>(wb + (size_t)kCA * kPlane + off);
        const int cai[4] = {(int)ca4.x, (int)ca4.y, (int)ca4.z, (int)ca4.w};
        #pragma unroll
        for (int j = 0; j < 4; ++j) {
            unsigned short p = (unsigned short)(lab[j] | (cai[j] << 8));
            if (lab[j] == kCloner) p |= 16;
            if (lab[j] == 0)       p |= 32;
            sPack[eh][4 * k + j] = p;
        }
    }
    __syncthreads();
    for (int idx = tid; idx < 34 * 34; idx += kThreads) {
        const int eh = idx / 34 + 1;
        const int lw = idx % 34 + 3;
        const unsigned short p = sPack[eh][lw];
        int fca = 0;
        if (p & 16) {
            int ca = (p >> 8) & 15;
            if (ca == 0 || ca == 13) ca = sPack[eh + 1][lw] & 15;
            if (ca == 0 || ca == 13) ca = sPack[eh - 1][lw] & 15;
            if (ca == 0 || ca == 13) ca = sPack[eh][lw - 1] & 15;
            if (ca == 0 || ca == 13) ca = sPack[eh][lw + 1] & 15;
            fca = ca;
        }
        unsigned short s = (unsigned short)(fca << 4);
        if (p & 32) s |= 1;
        if ((p & 16) && fca != 0 && fca != 13) s |= 2;
        sA[eh][lw] = s;
    }
    unsigned short (*prev)[kLW] = sA;
    unsigned short (*next)[kLW] = sB;
    {
        const int dh[4]   = {1, -1, 0, 0};
        const int dw[4]   = {0, 0, -1, 1};
        const int rhlo[4] = {1, 2, 2, 2};
        const int rhhi[4] = {33, 33, 33, 33};
        const int rwlo[4] = {3, 3, 4, 4};
        const int rwhi[4] = {36, 36, 36, 35};
        for (int d = 0; d < 4; ++d) {
            __syncthreads();
            const int nh = rhhi[d] - rhlo[d] + 1;
            const int nw = rwhi[d] - rwlo[d] + 1;
            for (int idx = tid; idx < nh * nw; idx += kThreads) {
                const int eh = rhlo[d] + idx / nw;
                const int lw = rwlo[d] + idx % nw;
                unsigned short s = prev[eh][lw];
                const unsigned short ns = prev[eh + dh[d]][lw + dw[d]];
                if ((ns & 2) && (s & 1)) {
                    const int v = (ns >> 4) & 15;
                    s = (unsigned short)((s & 0x00F0) | sVbits[v] | (v << 8) | 0x1000);
                }
                next[eh][lw] = s;
            }
            unsigned short (*t)[kLW] = prev; prev = next; next = t;
        }
    }
    __syncthreads();
    {
        const int th = tid >> 3;
        const int tw = (tid & 7) * 4;
        const int eh = th + 2;
        const size_t off = (size_t)(h0 + th) * kW + (w0 + tw);
        bool  o[4]; int src[4]; float fcaf[4]; int lb[4];
        #pragma unroll
        for (int j = 0; j < 4; ++j) {
            const unsigned short s = prev[eh][tw + 4 + j];
            o[j]    = (s & 0x1000) != 0;
            src[j]  = (s >> 8) & 15;
            fcaf[j] = (float)((s >> 4) & 15);
            lb[j]   = sPack[eh][tw + 4 + j] & 15;
        }
        #pragma unroll
        for (int c = 0; c < kNC; ++c) {
            float base[4];
            if (c >= kNE && c != kCA) {
                const float4 v = *reinterpret_cast<const float4*>(wb + (size_t)c * kPlane + off);
                base[0] = v.x; base[1] = v.y; base[2] = v.z; base[3] = v.w;
            } else if (c == kCA) {
                base[0] = fcaf[0]; base[1] = fcaf[1]; base[2] = fcaf[2]; base[3] = fcaf[3];
            } else {
                #pragma unroll
                for (int j = 0; j < 4; ++j) base[j] = (lb[j] == c) ? 1.0f : 0.0f;
            }
            float4 r;
            r.x = o[0] ? sEV[src[0] * kNC + c] : base[0];
            r.y = o[1] ? sEV[src[1] * kNC + c] : base[1];
            r.z = o[2] ? sEV[src[2] * kNC + c] : base[2];
            r.w = o[3] ? sEV[src[3] * kNC + c] : base[3];
            *reinterpret_cast<float4*>(ob + (size_t)c * kPlane + off) = r;
        }
    }
    if (blockIdx.x == 0 && blockIdx.y == 0 && blockIdx.z == 0 && tid < kB) {
        out[(size_t)kB * kNC * kPlane + tid] = info[tid];
    }
}

extern "C" void kernel_launch(void* const* d_in, const int* in_sizes, int n_in,
                              void* d_out, int out_size, void* d_ws, size_t ws_size,
                              hipStream_t stream) {
    const float* world = (const float*)d_in[0];
    const float* ev    = (const float*)d_in[1];
    const float* info  = (const float*)d_in[2];
    float* out = (float*)d_out;
    const size_t packBytes = (size_t)kB * kPlane;   // 2.1 MB (uint8)
    if (ws_size >= packBytes) {
        unsigned char* pack = (unsigned char*)d_ws;
        k_pack_copy<<<dim3((kB * (int)kPlane / 4) / kThreads), kThreads, 0, stream>>>(world, info, out, pack);
        k_ca<<<dim3(kW / kT, kH / kT, kB), kThreads, 0, stream>>>(ev, pack, out);
    } else {
        bc_fused<<<dim3(kW / kT, kH / kT, kB), kThreads, 0, stream>>>(world, ev, info, out);
    }
}

// Round 7
// 69.306 us; speedup vs baseline: 1.2511x; 1.2511x over previous
//
#include <hip/hip_runtime.h>

namespace {
constexpr int kNE = 14;
constexpr int kNC = 20;
constexpr int kCloner = 13;
constexpr int kCA = 17;   // NE + 3
constexpr int kB = 32;
constexpr int kH = 256;
constexpr int kW = 256;

constexpr int kSH = 4;        // K2 stripe height (full width)
constexpr int kThreads = 256;
constexpr size_t kPlane = (size_t)kH * kW;

// fallback tile geometry (round-3 kernel)
constexpr int kT = 32;
constexpr int kE = kT + 4;
constexpr int kLW = 40;
}

// pack (uint8): bits0..3 label (argmax of one-hot 0..13) | bits4..7 ca_init
// CA state (uint16): bit0 empty | bit1 active | bits4..7 fca | bits8..11 src | bit12 overwritten

// ---------------- K1: per-pixel pack, pure streaming (15R streams, 1W) ----------------
__global__ __launch_bounds__(kThreads)
void k_pack(const float* __restrict__ world, const float* __restrict__ info,
            float* __restrict__ out, unsigned char* __restrict__ pack)
{
    const int g = blockIdx.x * kThreads + threadIdx.x;   // 524288 float4-groups
    const int b = g >> 14;                                // 16384 groups per plane
    const int rem = g & 16383;
    const size_t off = (size_t)rem << 2;
    const float* wb = world + (size_t)b * kNC * kPlane;

    int lab[4] = {0, 0, 0, 0};
    #pragma unroll
    for (int c = 0; c < kNE; ++c) {
        const float4 v = *reinterpret_cast<const float4*>(wb + (size_t)c * kPlane + off);
        if (v.x > 0.5f) lab[0] = c;      // exact one-hot: unique channel holds 1.0
        if (v.y > 0.5f) lab[1] = c;
        if (v.z > 0.5f) lab[2] = c;
        if (v.w > 0.5f) lab[3] = c;
    }
    const float4 ca4 = *reinterpret_cast<const float4*>(wb + (size_t)kCA * kPlane + off);
    uchar4 p;
    p.x = (unsigned char)(lab[0] | ((int)ca4.x << 4));
    p.y = (unsigned char)(lab[1] | ((int)ca4.y << 4));
    p.z = (unsigned char)(lab[2] | ((int)ca4.z << 4));
    p.w = (unsigned char)(lab[3] | ((int)ca4.w << 4));
    *reinterpret_cast<uchar4*>(pack + (size_t)b * kPlane + off) = p;

    if (g < kB) out[(size_t)kB * kNC * kPlane + g] = info[g];   // info passthrough
}

// one mask-evolution step: self s, neighbor ns (both CA-state words)
__device__ __forceinline__ unsigned bc_step(unsigned s, unsigned ns,
                                            const unsigned short* __restrict__ vb) {
    if ((ns & 2u) && (s & 1u)) {
        const unsigned v = (ns >> 4) & 15u;
        return (s & 0x00F0u) | vb[v] | (v << 8) | 0x1000u;
    }
    return s;
}

// ---------------- K2: full-width stripe (4 rows x 256 cols), contiguous wave writes ----
__global__ __launch_bounds__(kThreads)
void k_apply(const float* __restrict__ world, const float* __restrict__ ev,
             const unsigned char* __restrict__ pack, float* __restrict__ out)
{
    __shared__ unsigned char  sP[kSH + 4][kW];   // rows y0-2 .. y0+5 (wrapped)
    __shared__ unsigned short sA[kSH + 2][kW];   // CA state rows y0-1 .. y0+4
    __shared__ float sEV[kNE * kNC];
    __shared__ unsigned short sVbits[kNE];

    const int tid = threadIdx.x;
    const int y0 = blockIdx.x * kSH;
    const int b  = blockIdx.y;
    const float* wb = world + (size_t)b * kNC * kPlane;
    float*       ob = out   + (size_t)b * kNC * kPlane;
    const unsigned char* pb = pack + (size_t)b * kPlane;

    // Per-thread output location: row th (0..3), cols col4..col4+3 (wave = 1 full row).
    const int th   = tid >> 6;
    const int col4 = (tid & 63) * 4;
    const size_t off4 = (size_t)(y0 + th) * kW + col4;

    // Early-issue pass-through channel loads (latency hides under LDS phases).
    float4 extra[5];
    extra[0] = *reinterpret_cast<const float4*>(wb + (size_t)14 * kPlane + off4);
    extra[1] = *reinterpret_cast<const float4*>(wb + (size_t)15 * kPlane + off4);
    extra[2] = *reinterpret_cast<const float4*>(wb + (size_t)16 * kPlane + off4);
    extra[3] = *reinterpret_cast<const float4*>(wb + (size_t)18 * kPlane + off4);
    extra[4] = *reinterpret_cast<const float4*>(wb + (size_t)19 * kPlane + off4);

    for (int i = tid; i < kNE * kNC; i += kThreads) sEV[i] = ev[i];
    if (tid < kNE) {
        const float e0  = ev[tid * kNC + 0];
        const float c13 = ev[tid * kNC + kCloner];
        const float c17 = ev[tid * kNC + kCA];
        unsigned short vb = 0;
        if (e0 > 0.5f) vb |= 1;                                     // empty after overwrite
        if (c13 > 0.5f && c17 != 0.0f && c17 != 13.0f) vb |= 2;     // active after overwrite
        sVbits[tid] = vb;
    }

    // pack rows y0-2..y0+5 (uchar4, contiguous per row; row wrap via &255)
    for (int idx = tid; idx < (kSH + 4) * (kW / 4); idx += kThreads) {
        const int r  = idx >> 6;            // 0..7
        const int c4 = (idx & 63) * 4;
        const int h  = (y0 - 2 + r) & (kH - 1);
        *reinterpret_cast<uchar4*>(&sP[r][c4]) =
            *reinterpret_cast<const uchar4*>(pb + (size_t)h * kW + c4);
    }
    __syncthreads();

    // phase A: final CA + state init on rows y0-1..y0+4 (sP rows 1..6), full width
    for (int idx = tid; idx < (kSH + 2) * kW; idx += kThreads) {
        const int r   = idx >> 8;           // 0..5 (sA row)
        const int col = idx & 255;
        const int pr  = r + 1;              // sP row
        const unsigned p  = sP[pr][col];
        const unsigned lb = p & 15u;
        int fca = 0;
        if (lb == kCloner) {                // cloner: sequentially absorb neighbor labels
            int ca = (int)(p >> 4);
            if (ca == 0 || ca == 13) ca = sP[pr + 1][col] & 15;            // below
            if (ca == 0 || ca == 13) ca = sP[pr - 1][col] & 15;            // above
            if (ca == 0 || ca == 13) ca = sP[pr][(col - 1) & 255] & 15;    // left
            if (ca == 0 || ca == 13) ca = sP[pr][(col + 1) & 255] & 15;    // right
            fca = ca;
        }
        unsigned short s = (unsigned short)(fca << 4);
        if (lb == 0) s |= 1;                                  // empty
        if (lb == kCloner && fca != 0 && fca != 13) s |= 2;   // active
        sA[r][col] = s;
    }
    __syncthreads();

    // phase B in registers: 4 direction steps over the 3x6 cone (column-wrapped)
    const int ar = th + 1;                  // sA row of the output row
    unsigned s0[3][6];
    #pragma unroll
    for (int r = 0; r < 3; ++r)
        #pragma unroll
        for (int c = 0; c < 6; ++c)
            s0[r][c] = sA[ar - 1 + r][(col4 - 1 + c) & 255];

    unsigned s1[2][6];
    #pragma unroll
    for (int r = 0; r < 2; ++r)
        #pragma unroll
        for (int c = 0; c < 6; ++c)
            s1[r][c] = bc_step(s0[r][c], s0[r + 1][c], sVbits);   // below

    unsigned s2[6];
    #pragma unroll
    for (int c = 0; c < 6; ++c)
        s2[c] = bc_step(s1[1][c], s1[0][c], sVbits);              // above

    unsigned s3[5];
    #pragma unroll
    for (int c = 0; c < 5; ++c)
        s3[c] = bc_step(s2[c + 1], s2[c], sVbits);                // left

    unsigned s4[4];
    #pragma unroll
    for (int j = 0; j < 4; ++j)
        s4[j] = bc_step(s3[j], s3[j + 1], sVbits);                // right

    bool  o[4]; int src[4]; float fcaf[4]; int lb[4];
    #pragma unroll
    for (int j = 0; j < 4; ++j) {
        o[j]    = (s4[j] & 0x1000u) != 0;
        src[j]  = (s4[j] >> 8) & 15;
        fcaf[j] = (float)((s4[j] >> 4) & 15);
        lb[j]   = sP[th + 2][col4 + j] & 15;
    }

    // write all 20 channels; each wave-store = 1024 contiguous bytes of one plane-row
    #pragma unroll
    for (int c = 0; c < kNC; ++c) {
        float base[4];
        if (c < kNE) {
            #pragma unroll
            for (int j = 0; j < 4; ++j) base[j] = (lb[j] == c) ? 1.0f : 0.0f;
        } else if (c == kCA) {
            #pragma unroll
            for (int j = 0; j < 4; ++j) base[j] = fcaf[j];
        } else {
            const float4 v = extra[c < kCA ? c - kNE : c - kNE - 1];
            base[0] = v.x; base[1] = v.y; base[2] = v.z; base[3] = v.w;
        }
        float4 r;
        r.x = o[0] ? sEV[src[0] * kNC + c] : base[0];
        r.y = o[1] ? sEV[src[1] * kNC + c] : base[1];
        r.z = o[2] ? sEV[src[2] * kNC + c] : base[2];
        r.w = o[3] ? sEV[src[3] * kNC + c] : base[3];
        *reinterpret_cast<float4*>(ob + (size_t)c * kPlane + off4) = r;
    }
}

// ---------------- Fallback (round-3 fused kernel), used only if ws too small ----------
__global__ __launch_bounds__(kThreads)
void bc_fused(const float* __restrict__ world, const float* __restrict__ ev,
              const float* __restrict__ info, float* __restrict__ out)
{
    __shared__ unsigned short sPack[kE][kLW];
    __shared__ unsigned short sA[kE][kLW];
    __shared__ unsigned short sB[kE][kLW];
    __shared__ float sEV[kNE * kNC];
    __shared__ unsigned short sVbits[kNE];

    const int tid = threadIdx.x;
    const int b  = blockIdx.z;
    const int h0 = blockIdx.y * kT;
    const int w0 = blockIdx.x * kT;
    const float* wb = world + (size_t)b * kNC * kPlane;
    float*       ob = out   + (size_t)b * kNC * kPlane;

    for (int i = tid; i < kNE * kNC; i += kThreads) sEV[i] = ev[i];
    if (tid < kNE) {
        const float e0  = ev[tid * kNC + 0];
        const float c13 = ev[tid * kNC + kCloner];
        const float c17 = ev[tid * kNC + kCA];
        unsigned short vb = 0;
        if (e0 > 0.5f) vb |= 1;
        if (c13 > 0.5f && c17 != 0.0f && c17 != 13.0f) vb |= 2;
        sVbits[tid] = vb;
    }
    for (int idx = tid; idx < kE * 10; idx += kThreads) {
        const int eh = idx / 10;
        const int k  = idx - eh * 10;
        const int h = (h0 + eh - 2) & (kH - 1);
        const int w = (w0 - 4 + 4 * k) & (kW - 1);
        const size_t off = (size_t)h * kW + w;
        int lab[4] = {0,0,0,0};
        #pragma unroll
        for (int c = 0; c < kNE; ++c) {
            const float4 v = *reinterpret_cast<const float4*>(wb + (size_t)c * kPlane + off);
            if (v.x > 0.5f) lab[0] = c;
            if (v.y > 0.5f) lab[1] = c;
            if (v.z > 0.5f) lab[2] = c;
            if (v.w > 0.5f) lab[3] = c;
        }
        const float4 ca4 = *reinterpret_cast<const float4*>(wb + (size_t)kCA * kPlane + off);
        const int cai[4] = {(int)ca4.x, (int)ca4.y, (int)ca4.z, (int)ca4.w};
        #pragma unroll
        for (int j = 0; j < 4; ++j) {
            unsigned short p = (unsigned short)(lab[j] | (cai[j] << 8));
            if (lab[j] == kCloner) p |= 16;
            if (lab[j] == 0)       p |= 32;
            sPack[eh][4 * k + j] = p;
        }
    }
    __syncthreads();
    for (int idx = tid; idx < 34 * 34; idx += kThreads) {
        const int eh = idx / 34 + 1;
        const int lw = idx % 34 + 3;
        const unsigned short p = sPack[eh][lw];
        int fca = 0;
        if (p & 16) {
            int ca = (p >> 8) & 15;
            if (ca == 0 || ca == 13) ca = sPack[eh + 1][lw] & 15;
            if (ca == 0 || ca == 13) ca = sPack[eh - 1][lw] & 15;
            if (ca == 0 || ca == 13) ca = sPack[eh][lw - 1] & 15;
            if (ca == 0 || ca == 13) ca = sPack[eh][lw + 1] & 15;
            fca = ca;
        }
        unsigned short s = (unsigned short)(fca << 4);
        if (p & 32) s |= 1;
        if ((p & 16) && fca != 0 && fca != 13) s |= 2;
        sA[eh][lw] = s;
    }
    unsigned short (*prev)[kLW] = sA;
    unsigned short (*next)[kLW] = sB;
    {
        const int dh[4]   = {1, -1, 0, 0};
        const int dw[4]   = {0, 0, -1, 1};
        const int rhlo[4] = {1, 2, 2, 2};
        const int rhhi[4] = {33, 33, 33, 33};
        const int rwlo[4] = {3, 3, 4, 4};
        const int rwhi[4] = {36, 36, 36, 35};
        for (int d = 0; d < 4; ++d) {
            __syncthreads();
            const int nh = rhhi[d] - rhlo[d] + 1;
            const int nw = rwhi[d] - rwlo[d] + 1;
            for (int idx = tid; idx < nh * nw; idx += kThreads) {
                const int eh = rhlo[d] + idx / nw;
                const int lw = rwlo[d] + idx % nw;
                unsigned short s = prev[eh][lw];
                const unsigned short ns = prev[eh + dh[d]][lw + dw[d]];
                if ((ns & 2) && (s & 1)) {
                    const int v = (ns >> 4) & 15;
                    s = (unsigned short)((s & 0x00F0) | sVbits[v] | (v << 8) | 0x1000);
                }
                next[eh][lw] = s;
            }
            unsigned short (*t)[kLW] = prev; prev = next; next = t;
        }
    }
    __syncthreads();
    {
        const int th = tid >> 3;
        const int tw = (tid & 7) * 4;
        const int eh = th + 2;
        const size_t off = (size_t)(h0 + th) * kW + (w0 + tw);
        bool  o[4]; int src[4]; float fcaf[4]; int lb[4];
        #pragma unroll
        for (int j = 0; j < 4; ++j) {
            const unsigned short s = prev[eh][tw + 4 + j];
            o[j]    = (s & 0x1000) != 0;
            src[j]  = (s >> 8) & 15;
            fcaf[j] = (float)((s >> 4) & 15);
            lb[j]   = sPack[eh][tw + 4 + j] & 15;
        }
        #pragma unroll
        for (int c = 0; c < kNC; ++c) {
            float base[4];
            if (c >= kNE && c != kCA) {
                const float4 v = *reinterpret_cast<const float4*>(wb + (size_t)c * kPlane + off);
                base[0] = v.x; base[1] = v.y; base[2] = v.z; base[3] = v.w;
            } else if (c == kCA) {
                base[0] = fcaf[0]; base[1] = fcaf[1]; base[2] = fcaf[2]; base[3] = fcaf[3];
            } else {
                #pragma unroll
                for (int j = 0; j < 4; ++j) base[j] = (lb[j] == c) ? 1.0f : 0.0f;
            }
            float4 r;
            r.x = o[0] ? sEV[src[0] * kNC + c] : base[0];
            r.y = o[1] ? sEV[src[1] * kNC + c] : base[1];
            r.z = o[2] ? sEV[src[2] * kNC + c] : base[2];
            r.w = o[3] ? sEV[src[3] * kNC + c] : base[3];
            *reinterpret_cast<float4*>(ob + (size_t)c * kPlane + off) = r;
        }
    }
    if (blockIdx.x == 0 && blockIdx.y == 0 && blockIdx.z == 0 && tid < kB) {
        out[(size_t)kB * kNC * kPlane + tid] = info[tid];
    }
}

extern "C" void kernel_launch(void* const* d_in, const int* in_sizes, int n_in,
                              void* d_out, int out_size, void* d_ws, size_t ws_size,
                              hipStream_t stream) {
    const float* world = (const float*)d_in[0];
    const float* ev    = (const float*)d_in[1];
    const float* info  = (const float*)d_in[2];
    float* out = (float*)d_out;
    const size_t packBytes = (size_t)kB * kPlane;   // 2.1 MB (uint8)
    if (ws_size >= packBytes) {
        unsigned char* pack = (unsigned char*)d_ws;
        k_pack<<<dim3((kB * (int)kPlane / 4) / kThreads), kThreads, 0, stream>>>(world, info, out, pack);
        k_apply<<<dim3(kH / kSH, kB), kThreads, 0, stream>>>(world, ev, pack, out);
    } else {
        bc_fused<<<dim3(kW / kT, kH / kT, kB), kThreads, 0, stream>>>(world, ev, info, out);
    }
}